// Round 4
// baseline (237.656 us; speedup 1.0000x reference)
//
#include <hip/hip_runtime.h>
#include <stdint.h>

#define NBOX 25200
#define BATCH 32
#define TOPK 1024
#define MAXDET 300
#define BINCAP 2048
#define CANDCAP 16384
#define CONF_T 0.25f
#define IOU_T 0.45f
#define KEY_BIAS 0x3E800001u   // conf > 0.25 => bits(conf) >= 0x3E800001; key in [0, 0x00FFFFFF]

// ---- workspace layout (bytes) ----
#define WS_HIST_OFF 0u                    // 32*256*4 = 32768
#define WS_CNT_OFF  32768u                // 32*4 = 128
#define WS_CAND_OFF 40960u                // 32*16384*8 = 4 MiB
#define WS_NEED     (40960u + (unsigned)BATCH * CANDCAP * 8u)

// ================= kernel A: per-slice histogram + candidate extraction =================
__global__ __launch_bounds__(256) void hist_extract_kernel(const float* __restrict__ x,
                                                           unsigned* __restrict__ ghist,
                                                           unsigned* __restrict__ gcnt,
                                                           unsigned long long* __restrict__ gcand) {
    const int blk = blockIdx.x;
    const int b = blk >> 3;
    const int sl = blk & 7;
    const int tid = threadIdx.x;
    const int lane = tid & 63;
    const float* __restrict__ xb = x + (size_t)b * NBOX * 6;
    unsigned long long* __restrict__ cb = gcand + (size_t)b * CANDCAP;

    __shared__ unsigned hist[256];
    hist[tid] = 0;
    __syncthreads();

    const int n0 = sl * (NBOX / 8), n1 = n0 + (NBOX / 8);
    for (int n = n0 + tid; n < n1; n += 256) {
        float2 oc = *reinterpret_cast<const float2*>(xb + n * 6 + 4);
        float conf = oc.x * oc.y;
        bool take = conf > CONF_T;
        unsigned key = 0;
        if (take) {
            key = __float_as_uint(conf) - KEY_BIAS;
            atomicAdd(&hist[key >> 16], 1u);
        }
        unsigned long long m = __ballot(take);
        unsigned base = 0;
        if (lane == 0 && m) base = atomicAdd(&gcnt[b], (unsigned)__popcll(m));
        base = (unsigned)__shfl((int)base, 0);
        if (take) {
            unsigned pos = base + (unsigned)__popcll(m & ((1ull << lane) - 1ull));
            if (pos < CANDCAP)
                cb[pos] = ((unsigned long long)key << 32) | (unsigned)(~(unsigned)n);
        }
    }
    __syncthreads();
    if (hist[tid]) atomicAdd(&ghist[b * 256 + tid], hist[tid]);
}

// ================= kernel B: select + rank-sort + NMS + output =================
__global__ __launch_bounds__(1024) void nms_kernel(const float* __restrict__ x,
                                                   const unsigned* __restrict__ ghist,
                                                   const unsigned* __restrict__ gcnt,
                                                   const unsigned long long* __restrict__ gcand,
                                                   float* __restrict__ out) {
    const int b = blockIdx.x;
    const int tid = threadIdx.x;
    const int lane = tid & 63;
    const int wv = tid >> 6;
    const float* __restrict__ xb = x + (size_t)b * NBOX * 6;
    const unsigned long long* __restrict__ cb = gcand + (size_t)b * CANDCAP;

    __shared__ unsigned hist[256];
    __shared__ int sh_selbin;
    __shared__ unsigned sh_cnt;
    __shared__ unsigned long long cand[BINCAP];
    __shared__ unsigned long long keys[TOPK];
    __shared__ float4 bbox[TOPK];
    __shared__ float bar[TOPK];
    __shared__ float4 lbox[2][64];
    __shared__ float lar[2][64];
    __shared__ int listn[2];
    __shared__ int wcnt[16], wpre[16];
    __shared__ int sh_total;

    if (tid < 256) hist[tid] = ghist[b * 256 + tid];
    if (tid == 0) { sh_selbin = 0; sh_cnt = 0; }
    keys[tid] = 0ull;
    __syncthreads();

    // selbin = smallest bin whose suffix count >= TOPK (stays 0 if total < TOPK)
    if (tid < 64) {
        unsigned c0 = hist[tid*4+0], c1 = hist[tid*4+1];
        unsigned c2 = hist[tid*4+2], c3 = hist[tid*4+3];
        unsigned s3 = c3, s2 = c2 + s3, s1 = c1 + s2, s0 = c0 + s1;
        unsigned suf = s0;
        #pragma unroll
        for (int off = 1; off < 64; off <<= 1) {
            unsigned o = (unsigned)__shfl_down((int)suf, off);
            if (lane + off < 64) suf += o;
        }
        unsigned excl = suf - s0;
        unsigned S0 = excl+s0, S1 = excl+s1, S2 = excl+s2, S3 = excl+s3;
        if (S0 >= TOPK && S1 < TOPK) sh_selbin = tid*4+0;
        if (S1 >= TOPK && S2 < TOPK) sh_selbin = tid*4+1;
        if (S2 >= TOPK && S3 < TOPK) sh_selbin = tid*4+2;
        if (S3 >= TOPK && excl < TOPK) sh_selbin = tid*4+3;
    }
    __syncthreads();
    const unsigned selbin = (unsigned)sh_selbin;
    const int Ct = (int)min(gcnt[b], (unsigned)CANDCAP);

    // ---------- filter pre-compacted candidates: bin >= selbin ----------
    for (int i = tid; i < Ct; i += 1024) {
        unsigned long long pk = cb[i];
        bool take = ((unsigned)(pk >> 48)) >= selbin;   // key>>16 == pk>>48
        unsigned long long m = __ballot(take);
        unsigned base = 0;
        if (lane == 0 && m) base = atomicAdd(&sh_cnt, (unsigned)__popcll(m));
        base = (unsigned)__shfl((int)base, 0);
        if (take) {
            unsigned pos = base + (unsigned)__popcll(m & ((1ull << lane) - 1ull));
            if (pos < BINCAP) cand[pos] = pk;
        }
    }
    __syncthreads();
    const int C = (int)min(sh_cnt, (unsigned)BINCAP);

    // ---------- rank sort: exact top-1024 by (key desc, idx asc) ----------
    for (int e = tid; e < C; e += 1024) {
        unsigned long long mine = cand[e];
        int rank = 0;
        #pragma unroll 8
        for (int j = 0; j < C; ++j) rank += (cand[j] > mine) ? 1 : 0;
        if (rank < TOPK) keys[rank] = mine;
    }
    __syncthreads();

    // ---------- gather top-K boxes ----------
    unsigned long long kk = keys[tid];
    unsigned key24 = (unsigned)(kk >> 32);
    int n = (int)(~(unsigned)kk);
    bool alive = (kk != 0ull);
    if (n < 0 || n >= NBOX) { n = 0; alive = false; }
    float sc_ = __uint_as_float(key24 + KEY_BIAS);    // bit-exact conf
    float2 p01 = *reinterpret_cast<const float2*>(xb + n * 6);
    float2 p23 = *reinterpret_cast<const float2*>(xb + n * 6 + 2);
    float x1 = p01.x - p23.x * 0.5f, y1 = p01.y - p23.y * 0.5f;
    float x2 = p01.x + p23.x * 0.5f, y2 = p01.y + p23.y * 0.5f;
    float4 mybox = make_float4(x1, y1, x2, y2);
    float my_ar = (x2 - x1) * (y2 - y1);
    bbox[tid] = mybox;
    bar[tid] = my_ar;
    __syncthreads();

    // ---------- intra-chunk suppression mask (parallel) ----------
    const int cbase = tid & ~63;
    unsigned long long my_mask = 0ull;
    #pragma unroll 4
    for (int i = 0; i < 64; ++i) {
        float4 bi = bbox[cbase + i];
        float ai = bar[cbase + i];
        float xx1 = fmaxf(bi.x, mybox.x);
        float yy1 = fmaxf(bi.y, mybox.y);
        float xx2 = fminf(bi.z, mybox.z);
        float yy2 = fminf(bi.w, mybox.w);
        float iw = fmaxf(xx2 - xx1, 0.0f);
        float ih = fmaxf(yy2 - yy1, 0.0f);
        float inter = iw * ih;
        float iou = inter / (ai + my_ar - inter + 1e-9f);
        if (i < lane && iou > IOU_T) my_mask |= (1ull << i);
    }

    // ---------- blocked greedy NMS: 16 chunks, 1 barrier each ----------
    for (int c = 0; c < 16; ++c) {
        if (c > 0 && wv >= c && alive) {
            const int pb = (c - 1) & 1;
            const int m = listn[pb];
            bool sup = false;
            #pragma unroll 2
            for (int t = 0; t < m; ++t) {
                float4 bi = lbox[pb][t];
                float ai = lar[pb][t];
                float xx1 = fmaxf(bi.x, mybox.x);
                float yy1 = fmaxf(bi.y, mybox.y);
                float xx2 = fminf(bi.z, mybox.z);
                float yy2 = fminf(bi.w, mybox.w);
                float iw = fmaxf(xx2 - xx1, 0.0f);
                float ih = fmaxf(yy2 - yy1, 0.0f);
                float inter = iw * ih;
                float iou = inter / (ai + my_ar - inter + 1e-9f);
                sup = sup || (iou > IOU_T);
            }
            alive = !sup;
        }
        if (wv == c) {
            unsigned long long rem = __ballot(alive);
            unsigned long long kept = 0ull;
            while (rem) {
                int i = __ffsll((long long)rem) - 1;
                unsigned long long bit = 1ull << i;
                kept |= bit;
                unsigned long long row = __ballot((unsigned)((my_mask >> i) & 1ull));
                rem &= ~(row | bit);
            }
            alive = (kept >> lane) & 1ull;
            int nk = __popcll(kept);
            int rk = __popcll(kept & ((1ull << lane) - 1ull));
            if (alive) { lbox[c & 1][rk] = mybox; lar[c & 1][rk] = my_ar; }
            if (lane == 0) listn[c & 1] = nk;
        }
        __syncthreads();
    }

    // ---------- rank kept entries, write output ----------
    unsigned long long m = __ballot(alive);
    if (lane == 0) wcnt[wv] = __popcll(m);
    __syncthreads();
    if (tid == 0) {
        int acc = 0;
        for (int w2 = 0; w2 < 16; ++w2) { wpre[w2] = acc; acc += wcnt[w2]; }
        sh_total = acc;
    }
    __syncthreads();
    const int rank = wpre[wv] + (int)__popcll(m & ((1ull << lane) - 1ull));
    const int total = sh_total;

    float* __restrict__ ob = out + (size_t)b * MAXDET * 6;
    if (alive && rank < MAXDET) {
        ob[rank * 6 + 0] = mybox.x;
        ob[rank * 6 + 1] = mybox.y;
        ob[rank * 6 + 2] = mybox.z;
        ob[rank * 6 + 3] = mybox.w;
        ob[rank * 6 + 4] = sc_;
        ob[rank * 6 + 5] = 0.0f;
    }
    for (int r = tid; r < MAXDET; r += 1024) {
        if (r >= total) {
            #pragma unroll
            for (int cc = 0; cc < 6; ++cc) ob[r * 6 + cc] = 0.0f;
        }
    }
}

// ================= fallback: round-3 single-kernel (used only if ws too small) =================
__global__ __launch_bounds__(1024) void nms_single_kernel(const float* __restrict__ x,
                                                          float* __restrict__ out) {
    const int b = blockIdx.x;
    const int tid = threadIdx.x;
    const int lane = tid & 63;
    const int wv = tid >> 6;
    const float* __restrict__ xb = x + (size_t)b * NBOX * 6;

    __shared__ unsigned hist[256];
    __shared__ int sh_selbin;
    __shared__ unsigned sh_cnt;
    __shared__ unsigned long long cand[BINCAP];
    __shared__ unsigned long long keys[TOPK];
    __shared__ float4 bbox[TOPK];
    __shared__ float bar[TOPK];
    __shared__ float4 lbox[2][64];
    __shared__ float lar[2][64];
    __shared__ int listn[2];
    __shared__ int wcnt[16], wpre[16];
    __shared__ int sh_total;

    if (tid < 256) hist[tid] = 0;
    if (tid == 0) { sh_selbin = 0; sh_cnt = 0; }
    keys[tid] = 0ull;
    __syncthreads();
    for (int n = tid; n < NBOX; n += 1024) {
        float2 oc = *reinterpret_cast<const float2*>(xb + n * 6 + 4);
        float conf = oc.x * oc.y;
        if (conf > CONF_T) atomicAdd(&hist[(__float_as_uint(conf) - KEY_BIAS) >> 16], 1u);
    }
    __syncthreads();
    if (tid < 64) {
        unsigned c0 = hist[tid*4+0], c1 = hist[tid*4+1];
        unsigned c2 = hist[tid*4+2], c3 = hist[tid*4+3];
        unsigned s3 = c3, s2 = c2 + s3, s1 = c1 + s2, s0 = c0 + s1;
        unsigned suf = s0;
        #pragma unroll
        for (int off = 1; off < 64; off <<= 1) {
            unsigned o = (unsigned)__shfl_down((int)suf, off);
            if (lane + off < 64) suf += o;
        }
        unsigned excl = suf - s0;
        unsigned S0 = excl+s0, S1 = excl+s1, S2 = excl+s2, S3 = excl+s3;
        if (S0 >= TOPK && S1 < TOPK) sh_selbin = tid*4+0;
        if (S1 >= TOPK && S2 < TOPK) sh_selbin = tid*4+1;
        if (S2 >= TOPK && S3 < TOPK) sh_selbin = tid*4+2;
        if (S3 >= TOPK && excl < TOPK) sh_selbin = tid*4+3;
    }
    __syncthreads();
    const unsigned selbin = (unsigned)sh_selbin;
    for (int n = tid; n < NBOX; n += 1024) {
        float2 oc = *reinterpret_cast<const float2*>(xb + n * 6 + 4);
        float conf = oc.x * oc.y;
        bool take = false; unsigned key = 0;
        if (conf > CONF_T) {
            key = __float_as_uint(conf) - KEY_BIAS;
            take = ((key >> 16) >= selbin);
        }
        unsigned long long m = __ballot(take);
        unsigned base = 0;
        if (lane == 0 && m) base = atomicAdd(&sh_cnt, (unsigned)__popcll(m));
        base = (unsigned)__shfl((int)base, 0);
        if (take) {
            unsigned pos = base + (unsigned)__popcll(m & ((1ull << lane) - 1ull));
            if (pos < BINCAP)
                cand[pos] = ((unsigned long long)key << 32) | (unsigned)(~(unsigned)n);
        }
    }
    __syncthreads();
    const int C = (int)min(sh_cnt, (unsigned)BINCAP);
    for (int e = tid; e < C; e += 1024) {
        unsigned long long mine = cand[e];
        int rank = 0;
        #pragma unroll 8
        for (int j = 0; j < C; ++j) rank += (cand[j] > mine) ? 1 : 0;
        if (rank < TOPK) keys[rank] = mine;
    }
    __syncthreads();
    unsigned long long kk = keys[tid];
    unsigned key24 = (unsigned)(kk >> 32);
    int n = (int)(~(unsigned)kk);
    bool alive = (kk != 0ull);
    if (n < 0 || n >= NBOX) { n = 0; alive = false; }
    float sc_ = __uint_as_float(key24 + KEY_BIAS);
    float2 p01 = *reinterpret_cast<const float2*>(xb + n * 6);
    float2 p23 = *reinterpret_cast<const float2*>(xb + n * 6 + 2);
    float x1 = p01.x - p23.x * 0.5f, y1 = p01.y - p23.y * 0.5f;
    float x2 = p01.x + p23.x * 0.5f, y2 = p01.y + p23.y * 0.5f;
    float4 mybox = make_float4(x1, y1, x2, y2);
    float my_ar = (x2 - x1) * (y2 - y1);
    bbox[tid] = mybox;
    bar[tid] = my_ar;
    __syncthreads();
    const int cbase = tid & ~63;
    unsigned long long my_mask = 0ull;
    #pragma unroll 4
    for (int i = 0; i < 64; ++i) {
        float4 bi = bbox[cbase + i];
        float ai = bar[cbase + i];
        float xx1 = fmaxf(bi.x, mybox.x);
        float yy1 = fmaxf(bi.y, mybox.y);
        float xx2 = fminf(bi.z, mybox.z);
        float yy2 = fminf(bi.w, mybox.w);
        float iw = fmaxf(xx2 - xx1, 0.0f);
        float ih = fmaxf(yy2 - yy1, 0.0f);
        float inter = iw * ih;
        float iou = inter / (ai + my_ar - inter + 1e-9f);
        if (i < lane && iou > IOU_T) my_mask |= (1ull << i);
    }
    for (int c = 0; c < 16; ++c) {
        if (c > 0 && wv >= c && alive) {
            const int pb = (c - 1) & 1;
            const int m = listn[pb];
            bool sup = false;
            #pragma unroll 2
            for (int t = 0; t < m; ++t) {
                float4 bi = lbox[pb][t];
                float ai = lar[pb][t];
                float xx1 = fmaxf(bi.x, mybox.x);
                float yy1 = fmaxf(bi.y, mybox.y);
                float xx2 = fminf(bi.z, mybox.z);
                float yy2 = fminf(bi.w, mybox.w);
                float iw = fmaxf(xx2 - xx1, 0.0f);
                float ih = fmaxf(yy2 - yy1, 0.0f);
                float inter = iw * ih;
                float iou = inter / (ai + my_ar - inter + 1e-9f);
                sup = sup || (iou > IOU_T);
            }
            alive = !sup;
        }
        if (wv == c) {
            unsigned long long rem = __ballot(alive);
            unsigned long long kept = 0ull;
            while (rem) {
                int i = __ffsll((long long)rem) - 1;
                unsigned long long bit = 1ull << i;
                kept |= bit;
                unsigned long long row = __ballot((unsigned)((my_mask >> i) & 1ull));
                rem &= ~(row | bit);
            }
            alive = (kept >> lane) & 1ull;
            int nk = __popcll(kept);
            int rk = __popcll(kept & ((1ull << lane) - 1ull));
            if (alive) { lbox[c & 1][rk] = mybox; lar[c & 1][rk] = my_ar; }
            if (lane == 0) listn[c & 1] = nk;
        }
        __syncthreads();
    }
    unsigned long long m = __ballot(alive);
    if (lane == 0) wcnt[wv] = __popcll(m);
    __syncthreads();
    if (tid == 0) {
        int acc = 0;
        for (int w2 = 0; w2 < 16; ++w2) { wpre[w2] = acc; acc += wcnt[w2]; }
        sh_total = acc;
    }
    __syncthreads();
    const int rank = wpre[wv] + (int)__popcll(m & ((1ull << lane) - 1ull));
    const int total = sh_total;
    float* __restrict__ ob = out + (size_t)b * MAXDET * 6;
    if (alive && rank < MAXDET) {
        ob[rank * 6 + 0] = mybox.x;
        ob[rank * 6 + 1] = mybox.y;
        ob[rank * 6 + 2] = mybox.z;
        ob[rank * 6 + 3] = mybox.w;
        ob[rank * 6 + 4] = sc_;
        ob[rank * 6 + 5] = 0.0f;
    }
    for (int r = tid; r < MAXDET; r += 1024) {
        if (r >= total) {
            #pragma unroll
            for (int cc = 0; cc < 6; ++cc) ob[r * 6 + cc] = 0.0f;
        }
    }
}

extern "C" void kernel_launch(void* const* d_in, const int* in_sizes, int n_in,
                              void* d_out, int out_size, void* d_ws, size_t ws_size,
                              hipStream_t stream) {
    const float* x = (const float*)d_in[0];
    float* out = (float*)d_out;
    if (ws_size >= (size_t)WS_NEED) {
        char* ws = (char*)d_ws;
        unsigned* ghist = (unsigned*)(ws + WS_HIST_OFF);
        unsigned* gcnt = (unsigned*)(ws + WS_CNT_OFF);
        unsigned long long* gcand = (unsigned long long*)(ws + WS_CAND_OFF);
        hipMemsetAsync(d_ws, 0, WS_CAND_OFF, stream);   // zero hist + counters
        hipLaunchKernelGGL(hist_extract_kernel, dim3(BATCH * 8), dim3(256), 0, stream,
                           x, ghist, gcnt, gcand);
        hipLaunchKernelGGL(nms_kernel, dim3(BATCH), dim3(1024), 0, stream,
                           x, ghist, gcnt, gcand, out);
    } else {
        hipLaunchKernelGGL(nms_single_kernel, dim3(BATCH), dim3(1024), 0, stream, x, out);
    }
}

// Round 5
// 121.661 us; speedup vs baseline: 1.9534x; 1.9534x over previous
//
#include <hip/hip_runtime.h>
#include <stdint.h>

#define NBOX 25200
#define BATCH 32
#define TOPK 1024
#define MAXDET 300
#define BINCAP 2048
#define SEGCAP 512
#define NSEG 32
#define CONF_T 0.25f
#define IOU_T 0.45f
#define KEY_BIAS 0x3E800001u   // conf > 0.25 => bits(conf) >= 0x3E800001; key in [0, 0x00FFFFFF]

// ---- workspace layout (bytes) ----
#define SEGS_OFF   0u          // [32][32][512] u64  = 4194304
#define SEGCNT_OFF 4194304u    // [32][32] u32       = 4096
#define GHIST_OFF  4198400u    // [32][8][256] u32   = 262144
#define SORTED_OFF 4460544u    // [32][1024] u64     = 262144
#define SBOX_OFF   4722688u    // [32][1024] float4  = 524288
#define SAREA_OFF  5246976u    // [32][1024] f32     = 131072
#define MASKS_OFF  5378048u    // [32][16][64][16] u64 = 2097152
#define WS_NEED    7475200u

// ================= K1: extract candidates per wave-segment (no atomics to global) =================
__global__ __launch_bounds__(256) void k1_extract(const float* __restrict__ x,
                                                  unsigned long long* __restrict__ segs,
                                                  unsigned* __restrict__ segcnt,
                                                  unsigned* __restrict__ ghist) {
    const int blk = blockIdx.x;
    const int b = blk >> 3;
    const int sl = blk & 7;
    const int tid = threadIdx.x;
    const int lane = tid & 63;
    const int wv = tid >> 6;
    const int seg = sl * 4 + wv;
    const float* __restrict__ xb = x + (size_t)b * NBOX * 6;
    unsigned long long* __restrict__ sb = segs + ((size_t)b * NSEG + seg) * SEGCAP;

    __shared__ unsigned hist[256];
    hist[tid] = 0;
    __syncthreads();

    const int n0 = (seg * NBOX) / NSEG;
    const int n1 = ((seg + 1) * NBOX) / NSEG;
    unsigned base = 0;
    const unsigned long long lmask = (1ull << lane) - 1ull;
    for (int n = n0 + lane; n < n1; n += 64) {
        float2 oc = *reinterpret_cast<const float2*>(xb + n * 6 + 4);
        float conf = oc.x * oc.y;
        bool take = conf > CONF_T;
        unsigned key = 0;
        if (take) {
            key = __float_as_uint(conf) - KEY_BIAS;
            atomicAdd(&hist[key >> 16], 1u);
        }
        unsigned long long m = __ballot(take);
        if (take) {
            unsigned pos = base + (unsigned)__popcll(m & lmask);
            if (pos < SEGCAP)
                sb[pos] = ((unsigned long long)key << 32) | (unsigned)(~(unsigned)n);
        }
        base += (unsigned)__popcll(m);
    }
    if (lane == 0) segcnt[b * NSEG + seg] = min(base, (unsigned)SEGCAP);
    __syncthreads();
    ghist[(size_t)blk * 256 + tid] = hist[tid];
}

// ================= K2: selbin + filter + rank-sort + gather boxes =================
__global__ __launch_bounds__(1024) void k2_sort(const float* __restrict__ x,
                                                const unsigned long long* __restrict__ segs,
                                                const unsigned* __restrict__ segcnt,
                                                const unsigned* __restrict__ ghist,
                                                unsigned long long* __restrict__ sorted_g,
                                                float4* __restrict__ sbox,
                                                float* __restrict__ sarea) {
    const int b = blockIdx.x;
    const int tid = threadIdx.x;
    const int lane = tid & 63;
    const float* __restrict__ xb = x + (size_t)b * NBOX * 6;

    __shared__ unsigned hist[256];
    __shared__ int sh_selbin;
    __shared__ unsigned sh_cnt;
    __shared__ unsigned long long cand[BINCAP];
    __shared__ unsigned long long sortedl[TOPK];

    if (tid < 256) {
        unsigned h = 0;
        #pragma unroll
        for (int sl = 0; sl < 8; ++sl) h += ghist[((size_t)b * 8 + sl) * 256 + tid];
        hist[tid] = h;
    }
    if (tid == 0) { sh_selbin = 0; sh_cnt = 0; }
    sortedl[tid] = 0ull;
    __syncthreads();

    // selbin = smallest bin whose suffix count >= TOPK
    if (tid < 64) {
        unsigned c0 = hist[tid*4+0], c1 = hist[tid*4+1];
        unsigned c2 = hist[tid*4+2], c3 = hist[tid*4+3];
        unsigned s3 = c3, s2 = c2 + s3, s1 = c1 + s2, s0 = c0 + s1;
        unsigned suf = s0;
        #pragma unroll
        for (int off = 1; off < 64; off <<= 1) {
            unsigned o = (unsigned)__shfl_down((int)suf, off);
            if (lane + off < 64) suf += o;
        }
        unsigned excl = suf - s0;
        unsigned S0 = excl+s0, S1 = excl+s1, S2 = excl+s2, S3 = excl+s3;
        if (S0 >= TOPK && S1 < TOPK) sh_selbin = tid*4+0;
        if (S1 >= TOPK && S2 < TOPK) sh_selbin = tid*4+1;
        if (S2 >= TOPK && S3 < TOPK) sh_selbin = tid*4+2;
        if (S3 >= TOPK && excl < TOPK) sh_selbin = tid*4+3;
    }
    __syncthreads();
    const unsigned selbin = (unsigned)sh_selbin;

    // filter all segments: bin >= selbin -> LDS cand
    for (int seg = 0; seg < NSEG; ++seg) {
        const unsigned cnts = segcnt[b * NSEG + seg];
        const unsigned long long* __restrict__ sgp = segs + ((size_t)b * NSEG + seg) * SEGCAP;
        for (unsigned i = tid; i < cnts; i += 1024) {
            unsigned long long pk = sgp[i];
            bool take = ((unsigned)(pk >> 48)) >= selbin;
            unsigned long long m = __ballot(take);
            unsigned bb = 0;
            if (lane == 0 && m) bb = atomicAdd(&sh_cnt, (unsigned)__popcll(m));
            bb = (unsigned)__shfl((int)bb, 0);
            if (take) {
                unsigned pos = bb + (unsigned)__popcll(m & ((1ull << lane) - 1ull));
                if (pos < BINCAP) cand[pos] = pk;
            }
        }
    }
    __syncthreads();
    const int C = (int)min(sh_cnt, (unsigned)BINCAP);

    // rank-sort: exact top-1024 by (key desc, idx asc)
    for (int e = tid; e < C; e += 1024) {
        unsigned long long mine = cand[e];
        int rank = 0;
        #pragma unroll 8
        for (int j = 0; j < C; ++j) rank += (cand[j] > mine) ? 1 : 0;
        if (rank < TOPK) sortedl[rank] = mine;
    }
    __syncthreads();

    // epilogue: write sorted keys + gathered boxes/areas
    unsigned long long pk = sortedl[tid];
    sorted_g[(size_t)b * TOPK + tid] = pk;
    int n = (int)(~(unsigned)pk);
    if (n < 0 || n >= NBOX) n = 0;
    float2 p01 = *reinterpret_cast<const float2*>(xb + n * 6);
    float2 p23 = *reinterpret_cast<const float2*>(xb + n * 6 + 2);
    float x1 = p01.x - p23.x * 0.5f, y1 = p01.y - p23.y * 0.5f;
    float x2 = p01.x + p23.x * 0.5f, y2 = p01.y + p23.y * 0.5f;
    sbox[(size_t)b * TOPK + tid] = make_float4(x1, y1, x2, y2);
    sarea[(size_t)b * TOPK + tid] = (x2 - x1) * (y2 - y1);
}

// ================= K3: pairwise chunk suppression masks =================
__global__ __launch_bounds__(64) void k3_masks(const float4* __restrict__ sbox,
                                               const float* __restrict__ sarea,
                                               unsigned long long* __restrict__ masks) {
    const int p = blockIdx.x;       // pair index, ic <= jc, p = jc*(jc+1)/2 + ic
    const int b = blockIdx.y;
    const int j = threadIdx.x;

    int jc = (int)((sqrtf(8.0f * (float)p + 1.0f) - 1.0f) * 0.5f);
    while ((jc + 1) * (jc + 2) / 2 <= p) ++jc;
    while (jc * (jc + 1) / 2 > p) --jc;
    const int ic = p - jc * (jc + 1) / 2;

    __shared__ float4 ibox[64];
    __shared__ float iar[64];
    ibox[j] = sbox[(size_t)b * TOPK + ic * 64 + j];
    iar[j]  = sarea[(size_t)b * TOPK + ic * 64 + j];
    const float4 mb = sbox[(size_t)b * TOPK + jc * 64 + j];
    const float ma  = sarea[(size_t)b * TOPK + jc * 64 + j];
    __syncthreads();

    unsigned long long w = 0ull;
    #pragma unroll 4
    for (int i = 0; i < 64; ++i) {
        float4 bi = ibox[i];
        float ai = iar[i];
        float xx1 = fmaxf(bi.x, mb.x);
        float yy1 = fmaxf(bi.y, mb.y);
        float xx2 = fminf(bi.z, mb.z);
        float yy2 = fminf(bi.w, mb.w);
        float iw = fmaxf(xx2 - xx1, 0.0f);
        float ih = fmaxf(yy2 - yy1, 0.0f);
        float inter = iw * ih;
        float iou = inter / (ai + ma - inter + 1e-9f);
        bool bit = (iou > IOU_T) && (ic != jc || i < j);
        if (bit) w |= (1ull << i);
    }
    masks[(((size_t)b * 16 + jc) * 64 + j) * 16 + ic] = w;
}

// ================= K4: serial resolve (bit-ops only) + output =================
__global__ __launch_bounds__(1024) void k4_resolve(const unsigned long long* __restrict__ sorted_g,
                                                   const float4* __restrict__ sbox,
                                                   const unsigned long long* __restrict__ masks,
                                                   float* __restrict__ out) {
    const int b = blockIdx.x;
    const int tid = threadIdx.x;
    const int lane = tid & 63;
    const int wv = tid >> 6;

    __shared__ unsigned long long keptb[16];
    __shared__ int wcnt[16], wpre[16];
    __shared__ int sh_total;

    const unsigned long long pk = sorted_g[(size_t)b * TOPK + tid];
    bool alive = (pk != 0ull);
    const size_t mbase = (((size_t)b * 16 + wv) * 64 + lane) * 16;

    for (int c = 0; c < 16; ++c) {
        const unsigned long long wc = masks[mbase + c];   // garbage if wv < c (never used)
        if (wv == c) {
            unsigned long long rem = __ballot(alive);
            unsigned long long kept = 0ull;
            while (rem) {
                int i = __ffsll((long long)rem) - 1;
                unsigned long long bit = 1ull << i;
                kept |= bit;
                unsigned long long row = __ballot((unsigned)((wc >> i) & 1ull));
                rem &= ~(row | bit);
            }
            alive = (kept >> lane) & 1ull;
            if (lane == 0) keptb[c] = kept;
        }
        __syncthreads();
        if (wv > c && alive && (wc & keptb[c])) alive = false;
    }

    // rank kept entries, write output
    unsigned long long m = __ballot(alive);
    if (lane == 0) wcnt[wv] = __popcll(m);
    __syncthreads();
    if (tid == 0) {
        int acc = 0;
        for (int w2 = 0; w2 < 16; ++w2) { wpre[w2] = acc; acc += wcnt[w2]; }
        sh_total = acc;
    }
    __syncthreads();
    const int rank = wpre[wv] + (int)__popcll(m & ((1ull << lane) - 1ull));
    const int total = sh_total;

    float* __restrict__ ob = out + (size_t)b * MAXDET * 6;
    if (alive && rank < MAXDET) {
        float4 bx = sbox[(size_t)b * TOPK + tid];
        float sc_ = __uint_as_float((unsigned)(pk >> 32) + KEY_BIAS);
        ob[rank * 6 + 0] = bx.x;
        ob[rank * 6 + 1] = bx.y;
        ob[rank * 6 + 2] = bx.z;
        ob[rank * 6 + 3] = bx.w;
        ob[rank * 6 + 4] = sc_;
        ob[rank * 6 + 5] = 0.0f;
    }
    for (int r = tid; r < MAXDET; r += 1024) {
        if (r >= total) {
            #pragma unroll
            for (int cc = 0; cc < 6; ++cc) ob[r * 6 + cc] = 0.0f;
        }
    }
}

// ================= fallback: round-3 single-kernel (used only if ws too small) =================
__global__ __launch_bounds__(1024) void nms_single_kernel(const float* __restrict__ x,
                                                          float* __restrict__ out) {
    const int b = blockIdx.x;
    const int tid = threadIdx.x;
    const int lane = tid & 63;
    const int wv = tid >> 6;
    const float* __restrict__ xb = x + (size_t)b * NBOX * 6;

    __shared__ unsigned hist[256];
    __shared__ int sh_selbin;
    __shared__ unsigned sh_cnt;
    __shared__ unsigned long long cand[BINCAP];
    __shared__ unsigned long long keys[TOPK];
    __shared__ float4 bbox[TOPK];
    __shared__ float bar[TOPK];
    __shared__ float4 lbox[2][64];
    __shared__ float lar[2][64];
    __shared__ int listn[2];
    __shared__ int wcnt[16], wpre[16];
    __shared__ int sh_total;

    if (tid < 256) hist[tid] = 0;
    if (tid == 0) { sh_selbin = 0; sh_cnt = 0; }
    keys[tid] = 0ull;
    __syncthreads();
    for (int n = tid; n < NBOX; n += 1024) {
        float2 oc = *reinterpret_cast<const float2*>(xb + n * 6 + 4);
        float conf = oc.x * oc.y;
        if (conf > CONF_T) atomicAdd(&hist[(__float_as_uint(conf) - KEY_BIAS) >> 16], 1u);
    }
    __syncthreads();
    if (tid < 64) {
        unsigned c0 = hist[tid*4+0], c1 = hist[tid*4+1];
        unsigned c2 = hist[tid*4+2], c3 = hist[tid*4+3];
        unsigned s3 = c3, s2 = c2 + s3, s1 = c1 + s2, s0 = c0 + s1;
        unsigned suf = s0;
        #pragma unroll
        for (int off = 1; off < 64; off <<= 1) {
            unsigned o = (unsigned)__shfl_down((int)suf, off);
            if (lane + off < 64) suf += o;
        }
        unsigned excl = suf - s0;
        unsigned S0 = excl+s0, S1 = excl+s1, S2 = excl+s2, S3 = excl+s3;
        if (S0 >= TOPK && S1 < TOPK) sh_selbin = tid*4+0;
        if (S1 >= TOPK && S2 < TOPK) sh_selbin = tid*4+1;
        if (S2 >= TOPK && S3 < TOPK) sh_selbin = tid*4+2;
        if (S3 >= TOPK && excl < TOPK) sh_selbin = tid*4+3;
    }
    __syncthreads();
    const unsigned selbin = (unsigned)sh_selbin;
    for (int n = tid; n < NBOX; n += 1024) {
        float2 oc = *reinterpret_cast<const float2*>(xb + n * 6 + 4);
        float conf = oc.x * oc.y;
        bool take = false; unsigned key = 0;
        if (conf > CONF_T) {
            key = __float_as_uint(conf) - KEY_BIAS;
            take = ((key >> 16) >= selbin);
        }
        unsigned long long m = __ballot(take);
        unsigned base = 0;
        if (lane == 0 && m) base = atomicAdd(&sh_cnt, (unsigned)__popcll(m));
        base = (unsigned)__shfl((int)base, 0);
        if (take) {
            unsigned pos = base + (unsigned)__popcll(m & ((1ull << lane) - 1ull));
            if (pos < BINCAP)
                cand[pos] = ((unsigned long long)key << 32) | (unsigned)(~(unsigned)n);
        }
    }
    __syncthreads();
    const int C = (int)min(sh_cnt, (unsigned)BINCAP);
    for (int e = tid; e < C; e += 1024) {
        unsigned long long mine = cand[e];
        int rank = 0;
        #pragma unroll 8
        for (int j = 0; j < C; ++j) rank += (cand[j] > mine) ? 1 : 0;
        if (rank < TOPK) keys[rank] = mine;
    }
    __syncthreads();
    unsigned long long kk = keys[tid];
    unsigned key24 = (unsigned)(kk >> 32);
    int n = (int)(~(unsigned)kk);
    bool alive = (kk != 0ull);
    if (n < 0 || n >= NBOX) { n = 0; alive = false; }
    float sc_ = __uint_as_float(key24 + KEY_BIAS);
    float2 p01 = *reinterpret_cast<const float2*>(xb + n * 6);
    float2 p23 = *reinterpret_cast<const float2*>(xb + n * 6 + 2);
    float x1 = p01.x - p23.x * 0.5f, y1 = p01.y - p23.y * 0.5f;
    float x2 = p01.x + p23.x * 0.5f, y2 = p01.y + p23.y * 0.5f;
    float4 mybox = make_float4(x1, y1, x2, y2);
    float my_ar = (x2 - x1) * (y2 - y1);
    bbox[tid] = mybox;
    bar[tid] = my_ar;
    __syncthreads();
    const int cbase = tid & ~63;
    unsigned long long my_mask = 0ull;
    #pragma unroll 4
    for (int i = 0; i < 64; ++i) {
        float4 bi = bbox[cbase + i];
        float ai = bar[cbase + i];
        float xx1 = fmaxf(bi.x, mybox.x);
        float yy1 = fmaxf(bi.y, mybox.y);
        float xx2 = fminf(bi.z, mybox.z);
        float yy2 = fminf(bi.w, mybox.w);
        float iw = fmaxf(xx2 - xx1, 0.0f);
        float ih = fmaxf(yy2 - yy1, 0.0f);
        float inter = iw * ih;
        float iou = inter / (ai + my_ar - inter + 1e-9f);
        if (i < lane && iou > IOU_T) my_mask |= (1ull << i);
    }
    for (int c = 0; c < 16; ++c) {
        if (c > 0 && wv >= c && alive) {
            const int pb = (c - 1) & 1;
            const int m = listn[pb];
            bool sup = false;
            #pragma unroll 2
            for (int t = 0; t < m; ++t) {
                float4 bi = lbox[pb][t];
                float ai = lar[pb][t];
                float xx1 = fmaxf(bi.x, mybox.x);
                float yy1 = fmaxf(bi.y, mybox.y);
                float xx2 = fminf(bi.z, mybox.z);
                float yy2 = fminf(bi.w, mybox.w);
                float iw = fmaxf(xx2 - xx1, 0.0f);
                float ih = fmaxf(yy2 - yy1, 0.0f);
                float inter = iw * ih;
                float iou = inter / (ai + my_ar - inter + 1e-9f);
                sup = sup || (iou > IOU_T);
            }
            alive = !sup;
        }
        if (wv == c) {
            unsigned long long rem = __ballot(alive);
            unsigned long long kept = 0ull;
            while (rem) {
                int i = __ffsll((long long)rem) - 1;
                unsigned long long bit = 1ull << i;
                kept |= bit;
                unsigned long long row = __ballot((unsigned)((my_mask >> i) & 1ull));
                rem &= ~(row | bit);
            }
            alive = (kept >> lane) & 1ull;
            int nk = __popcll(kept);
            int rk = __popcll(kept & ((1ull << lane) - 1ull));
            if (alive) { lbox[c & 1][rk] = mybox; lar[c & 1][rk] = my_ar; }
            if (lane == 0) listn[c & 1] = nk;
        }
        __syncthreads();
    }
    unsigned long long m = __ballot(alive);
    if (lane == 0) wcnt[wv] = __popcll(m);
    __syncthreads();
    if (tid == 0) {
        int acc = 0;
        for (int w2 = 0; w2 < 16; ++w2) { wpre[w2] = acc; acc += wcnt[w2]; }
        sh_total = acc;
    }
    __syncthreads();
    const int rank = wpre[wv] + (int)__popcll(m & ((1ull << lane) - 1ull));
    const int total = sh_total;
    float* __restrict__ ob = out + (size_t)b * MAXDET * 6;
    if (alive && rank < MAXDET) {
        ob[rank * 6 + 0] = mybox.x;
        ob[rank * 6 + 1] = mybox.y;
        ob[rank * 6 + 2] = mybox.z;
        ob[rank * 6 + 3] = mybox.w;
        ob[rank * 6 + 4] = sc_;
        ob[rank * 6 + 5] = 0.0f;
    }
    for (int r = tid; r < MAXDET; r += 1024) {
        if (r >= total) {
            #pragma unroll
            for (int cc = 0; cc < 6; ++cc) ob[r * 6 + cc] = 0.0f;
        }
    }
}

extern "C" void kernel_launch(void* const* d_in, const int* in_sizes, int n_in,
                              void* d_out, int out_size, void* d_ws, size_t ws_size,
                              hipStream_t stream) {
    const float* x = (const float*)d_in[0];
    float* out = (float*)d_out;
    if (ws_size >= (size_t)WS_NEED) {
        char* ws = (char*)d_ws;
        unsigned long long* segs   = (unsigned long long*)(ws + SEGS_OFF);
        unsigned* segcnt           = (unsigned*)(ws + SEGCNT_OFF);
        unsigned* ghist            = (unsigned*)(ws + GHIST_OFF);
        unsigned long long* sorted = (unsigned long long*)(ws + SORTED_OFF);
        float4* sbox               = (float4*)(ws + SBOX_OFF);
        float* sarea               = (float*)(ws + SAREA_OFF);
        unsigned long long* masks  = (unsigned long long*)(ws + MASKS_OFF);
        hipLaunchKernelGGL(k1_extract, dim3(BATCH * 8), dim3(256), 0, stream,
                           x, segs, segcnt, ghist);
        hipLaunchKernelGGL(k2_sort, dim3(BATCH), dim3(1024), 0, stream,
                           x, segs, segcnt, ghist, sorted, sbox, sarea);
        hipLaunchKernelGGL(k3_masks, dim3(136, BATCH), dim3(64), 0, stream,
                           sbox, sarea, masks);
        hipLaunchKernelGGL(k4_resolve, dim3(BATCH), dim3(1024), 0, stream,
                           sorted, sbox, masks, out);
    } else {
        hipLaunchKernelGGL(nms_single_kernel, dim3(BATCH), dim3(1024), 0, stream, x, out);
    }
}

// Round 6
// 75.652 us; speedup vs baseline: 3.1414x; 1.6082x over previous
//
#include <hip/hip_runtime.h>
#include <stdint.h>

#define NBOX 25200
#define BATCH 32
#define TOPK 1024
#define MAXDET 300
#define BINCAP 2048
#define SEGCAP 512
#define NSEG 32
#define CONF_T 0.25f
#define IOU_T 0.45f
#define KEY_BIAS 0x3E800001u   // conf > 0.25 => bits(conf) >= 0x3E800001; key in [0, 0x00FFFFFF]

// ---- workspace layout (bytes) ----
#define SEGS_OFF   0u          // [32][32][512] u64  = 4194304
#define SEGCNT_OFF 4194304u    // [32][32] u32       = 4096
#define GHIST_OFF  4198400u    // [32][8][256] u32   = 262144
#define SORTED_OFF 4460544u    // [32][1024] u64     = 262144
#define SBOX_OFF   4722688u    // [32][1024] float4  = 524288
#define SAREA_OFF  5246976u    // [32][1024] f32     = 131072
#define MASKS_OFF  5378048u    // [32][16][16][64] u64 = 2097152  (b, jc, ic, j)
#define WS_NEED    7475200u

// ================= K1: extract candidates per wave-segment (no atomics to global) =================
__global__ __launch_bounds__(256) void k1_extract(const float* __restrict__ x,
                                                  unsigned long long* __restrict__ segs,
                                                  unsigned* __restrict__ segcnt,
                                                  unsigned* __restrict__ ghist) {
    const int blk = blockIdx.x;
    const int b = blk >> 3;
    const int sl = blk & 7;
    const int tid = threadIdx.x;
    const int lane = tid & 63;
    const int wv = tid >> 6;
    const int seg = sl * 4 + wv;
    const float* __restrict__ xb = x + (size_t)b * NBOX * 6;
    unsigned long long* __restrict__ sb = segs + ((size_t)b * NSEG + seg) * SEGCAP;

    __shared__ unsigned hist[256];
    hist[tid] = 0;
    __syncthreads();

    const int n0 = (seg * NBOX) / NSEG;
    const int n1 = ((seg + 1) * NBOX) / NSEG;
    unsigned base = 0;
    const unsigned long long lmask = (1ull << lane) - 1ull;
    for (int n = n0 + lane; n < n1; n += 64) {
        float2 oc = *reinterpret_cast<const float2*>(xb + n * 6 + 4);
        float conf = oc.x * oc.y;
        bool take = conf > CONF_T;
        unsigned key = 0;
        if (take) {
            key = __float_as_uint(conf) - KEY_BIAS;
            atomicAdd(&hist[key >> 16], 1u);
        }
        unsigned long long m = __ballot(take);
        if (take) {
            unsigned pos = base + (unsigned)__popcll(m & lmask);
            if (pos < SEGCAP)
                sb[pos] = ((unsigned long long)key << 32) | (unsigned)(~(unsigned)n);
        }
        base += (unsigned)__popcll(m);
    }
    if (lane == 0) segcnt[b * NSEG + seg] = min(base, (unsigned)SEGCAP);
    __syncthreads();
    ghist[(size_t)blk * 256 + tid] = hist[tid];
}

// ================= K2: selbin + bucket-scatter + within-bin rank + gather =================
__global__ __launch_bounds__(1024) void k2_sort(const float* __restrict__ x,
                                                const unsigned long long* __restrict__ segs,
                                                const unsigned* __restrict__ segcnt,
                                                const unsigned* __restrict__ ghist,
                                                unsigned long long* __restrict__ sorted_g,
                                                float4* __restrict__ sbox,
                                                float* __restrict__ sarea) {
    const int b = blockIdx.x;
    const int tid = threadIdx.x;
    const int lane = tid & 63;
    const float* __restrict__ xb = x + (size_t)b * NBOX * 6;
    const unsigned long long* __restrict__ segs_b = segs + (size_t)b * NSEG * SEGCAP;

    __shared__ unsigned hist[256];
    __shared__ unsigned binstart[256];   // descending-order start: sum of hist over bins > this one
    __shared__ unsigned bincnt[256];
    __shared__ int sh_selbin;
    __shared__ unsigned segcnt_l[NSEG];
    __shared__ unsigned long long cand[BINCAP];
    __shared__ unsigned long long sortedl[TOPK];

    if (tid < 256) {
        unsigned h = 0;
        #pragma unroll
        for (int sl = 0; sl < 8; ++sl) h += ghist[((size_t)b * 8 + sl) * 256 + tid];
        hist[tid] = h;
        bincnt[tid] = 0;
    }
    if (tid < NSEG) segcnt_l[tid] = segcnt[b * NSEG + tid];
    if (tid == 0) sh_selbin = 0;
    sortedl[tid] = 0ull;
    __syncthreads();

    // suffix sums -> binstart (descending order) + selbin
    if (tid < 64) {
        unsigned c0 = hist[tid*4+0], c1 = hist[tid*4+1];
        unsigned c2 = hist[tid*4+2], c3 = hist[tid*4+3];
        unsigned s3 = c3, s2 = c2 + s3, s1 = c1 + s2, s0 = c0 + s1;
        unsigned suf = s0;
        #pragma unroll
        for (int off = 1; off < 64; off <<= 1) {
            unsigned o = (unsigned)__shfl_down((int)suf, off);
            if (lane + off < 64) suf += o;
        }
        unsigned excl = suf - s0;                 // sum over groups > lane
        binstart[tid*4+0] = excl + s1;
        binstart[tid*4+1] = excl + s2;
        binstart[tid*4+2] = excl + s3;
        binstart[tid*4+3] = excl;
        unsigned S0 = excl+s0, S1 = excl+s1, S2 = excl+s2, S3 = excl+s3;
        if (S0 >= TOPK && S1 < TOPK) sh_selbin = tid*4+0;
        if (S1 >= TOPK && S2 < TOPK) sh_selbin = tid*4+1;
        if (S2 >= TOPK && S3 < TOPK) sh_selbin = tid*4+2;
        if (S3 >= TOPK && excl < TOPK) sh_selbin = tid*4+3;
    }
    __syncthreads();
    const unsigned selbin = (unsigned)sh_selbin;
    const int C = (int)min(binstart[selbin] + hist[selbin], (unsigned)BINCAP);

    // filter + bucket-scatter: flat over all segment slots
    for (int idx = tid; idx < NSEG * SEGCAP; idx += 1024) {
        const int seg = idx >> 9;           // /SEGCAP
        const int i = idx & (SEGCAP - 1);
        if (i < (int)segcnt_l[seg]) {
            unsigned long long pk = segs_b[idx];
            unsigned bin = (unsigned)(pk >> 48);
            if (bin >= selbin) {
                unsigned pos = binstart[bin] + atomicAdd(&bincnt[bin], 1u);
                if (pos < BINCAP) cand[pos] = pk;
            }
        }
    }
    __syncthreads();

    // within-bin exact rank (bins are disjoint, ordered descending)
    for (int e = tid; e < C; e += 1024) {
        unsigned long long mine = cand[e];
        unsigned bin = (unsigned)(mine >> 48);
        unsigned js = binstart[bin];
        unsigned je = min(js + hist[bin], (unsigned)C);
        int rank = (int)js;
        for (unsigned j = js; j < je; ++j) rank += (cand[j] > mine) ? 1 : 0;
        if (rank < TOPK) sortedl[rank] = mine;
    }
    __syncthreads();

    // epilogue: write sorted keys + gathered boxes/areas
    unsigned long long pk = sortedl[tid];
    sorted_g[(size_t)b * TOPK + tid] = pk;
    int n = (int)(~(unsigned)pk);
    if (n < 0 || n >= NBOX) n = 0;
    float2 p01 = *reinterpret_cast<const float2*>(xb + n * 6);
    float2 p23 = *reinterpret_cast<const float2*>(xb + n * 6 + 2);
    float x1 = p01.x - p23.x * 0.5f, y1 = p01.y - p23.y * 0.5f;
    float x2 = p01.x + p23.x * 0.5f, y2 = p01.y + p23.y * 0.5f;
    sbox[(size_t)b * TOPK + tid] = make_float4(x1, y1, x2, y2);
    sarea[(size_t)b * TOPK + tid] = (x2 - x1) * (y2 - y1);
}

// ================= K3: pairwise chunk suppression masks (4 pairs/block) =================
__global__ __launch_bounds__(256) void k3_masks(const float4* __restrict__ sbox,
                                                const float* __restrict__ sarea,
                                                unsigned long long* __restrict__ masks) {
    const int b = blockIdx.y;
    const int wv = threadIdx.x >> 6;
    const int j = threadIdx.x & 63;
    const int p = blockIdx.x * 4 + wv;          // 0..135, ic <= jc

    int jc = (int)((sqrtf(8.0f * (float)p + 1.0f) - 1.0f) * 0.5f);
    while ((jc + 1) * (jc + 2) / 2 <= p) ++jc;
    while (jc * (jc + 1) / 2 > p) --jc;
    const int ic = p - jc * (jc + 1) / 2;

    __shared__ float4 ibox[4][64];
    __shared__ float iar[4][64];
    ibox[wv][j] = sbox[(size_t)b * TOPK + ic * 64 + j];
    iar[wv][j]  = sarea[(size_t)b * TOPK + ic * 64 + j];
    const float4 mb = sbox[(size_t)b * TOPK + jc * 64 + j];
    const float ma  = sarea[(size_t)b * TOPK + jc * 64 + j];
    __syncthreads();

    unsigned long long w = 0ull;
    #pragma unroll 4
    for (int i = 0; i < 64; ++i) {
        float4 bi = ibox[wv][i];
        float ai = iar[wv][i];
        float xx1 = fmaxf(bi.x, mb.x);
        float yy1 = fmaxf(bi.y, mb.y);
        float xx2 = fminf(bi.z, mb.z);
        float yy2 = fminf(bi.w, mb.w);
        float iw = fmaxf(xx2 - xx1, 0.0f);
        float ih = fmaxf(yy2 - yy1, 0.0f);
        float inter = iw * ih;
        float iou = inter / (ai + ma - inter + 1e-9f);
        bool bit = (iou > IOU_T) && (ic != jc || i < j);
        if (bit) w |= (1ull << i);
    }
    masks[(((size_t)b * 16 + jc) * 16 + ic) * 64 + j] = w;   // lane-coalesced
}

// ================= K4: serial resolve (bit-ops only) + output =================
__global__ __launch_bounds__(1024) void k4_resolve(const unsigned long long* __restrict__ sorted_g,
                                                   const float4* __restrict__ sbox,
                                                   const unsigned long long* __restrict__ masks,
                                                   float* __restrict__ out) {
    const int b = blockIdx.x;
    const int tid = threadIdx.x;
    const int lane = tid & 63;
    const int wv = tid >> 6;

    __shared__ unsigned long long keptb[16];
    __shared__ int wcnt[16], wpre[16];
    __shared__ int sh_total;

    const unsigned long long pk = sorted_g[(size_t)b * TOPK + tid];
    bool alive = (pk != 0ull);

    // prefetch this thread's 16 chunk-masks (coalesced; entries with c > wv are unused garbage)
    unsigned long long wcs[16];
    #pragma unroll
    for (int c = 0; c < 16; ++c)
        wcs[c] = masks[(((size_t)b * 16 + wv) * 16 + c) * 64 + lane];

    #pragma unroll
    for (int c = 0; c < 16; ++c) {
        if (wv == c) {
            unsigned long long rem = __ballot(alive);
            unsigned long long kept = 0ull;
            while (rem) {
                int i = __ffsll((long long)rem) - 1;
                unsigned long long bit = 1ull << i;
                kept |= bit;
                unsigned long long row = __ballot((unsigned)((wcs[c] >> i) & 1ull));
                rem &= ~(row | bit);
            }
            alive = (kept >> lane) & 1ull;
            if (lane == 0) keptb[c] = kept;
        }
        __syncthreads();
        if (wv > c && alive && (wcs[c] & keptb[c])) alive = false;
    }

    // rank kept entries, write output
    unsigned long long m = __ballot(alive);
    if (lane == 0) wcnt[wv] = __popcll(m);
    __syncthreads();
    if (tid == 0) {
        int acc = 0;
        for (int w2 = 0; w2 < 16; ++w2) { wpre[w2] = acc; acc += wcnt[w2]; }
        sh_total = acc;
    }
    __syncthreads();
    const int rank = wpre[wv] + (int)__popcll(m & ((1ull << lane) - 1ull));
    const int total = sh_total;

    float* __restrict__ ob = out + (size_t)b * MAXDET * 6;
    if (alive && rank < MAXDET) {
        float4 bx = sbox[(size_t)b * TOPK + tid];
        float sc_ = __uint_as_float((unsigned)(pk >> 32) + KEY_BIAS);
        ob[rank * 6 + 0] = bx.x;
        ob[rank * 6 + 1] = bx.y;
        ob[rank * 6 + 2] = bx.z;
        ob[rank * 6 + 3] = bx.w;
        ob[rank * 6 + 4] = sc_;
        ob[rank * 6 + 5] = 0.0f;
    }
    for (int r = tid; r < MAXDET; r += 1024) {
        if (r >= total) {
            #pragma unroll
            for (int cc = 0; cc < 6; ++cc) ob[r * 6 + cc] = 0.0f;
        }
    }
}

// ================= fallback: round-3 single-kernel (used only if ws too small) =================
__global__ __launch_bounds__(1024) void nms_single_kernel(const float* __restrict__ x,
                                                          float* __restrict__ out) {
    const int b = blockIdx.x;
    const int tid = threadIdx.x;
    const int lane = tid & 63;
    const int wv = tid >> 6;
    const float* __restrict__ xb = x + (size_t)b * NBOX * 6;

    __shared__ unsigned hist[256];
    __shared__ int sh_selbin;
    __shared__ unsigned sh_cnt;
    __shared__ unsigned long long cand[BINCAP];
    __shared__ unsigned long long keys[TOPK];
    __shared__ float4 bbox[TOPK];
    __shared__ float bar[TOPK];
    __shared__ float4 lbox[2][64];
    __shared__ float lar[2][64];
    __shared__ int listn[2];
    __shared__ int wcnt[16], wpre[16];
    __shared__ int sh_total;

    if (tid < 256) hist[tid] = 0;
    if (tid == 0) { sh_selbin = 0; sh_cnt = 0; }
    keys[tid] = 0ull;
    __syncthreads();
    for (int n = tid; n < NBOX; n += 1024) {
        float2 oc = *reinterpret_cast<const float2*>(xb + n * 6 + 4);
        float conf = oc.x * oc.y;
        if (conf > CONF_T) atomicAdd(&hist[(__float_as_uint(conf) - KEY_BIAS) >> 16], 1u);
    }
    __syncthreads();
    if (tid < 64) {
        unsigned c0 = hist[tid*4+0], c1 = hist[tid*4+1];
        unsigned c2 = hist[tid*4+2], c3 = hist[tid*4+3];
        unsigned s3 = c3, s2 = c2 + s3, s1 = c1 + s2, s0 = c0 + s1;
        unsigned suf = s0;
        #pragma unroll
        for (int off = 1; off < 64; off <<= 1) {
            unsigned o = (unsigned)__shfl_down((int)suf, off);
            if (lane + off < 64) suf += o;
        }
        unsigned excl = suf - s0;
        unsigned S0 = excl+s0, S1 = excl+s1, S2 = excl+s2, S3 = excl+s3;
        if (S0 >= TOPK && S1 < TOPK) sh_selbin = tid*4+0;
        if (S1 >= TOPK && S2 < TOPK) sh_selbin = tid*4+1;
        if (S2 >= TOPK && S3 < TOPK) sh_selbin = tid*4+2;
        if (S3 >= TOPK && excl < TOPK) sh_selbin = tid*4+3;
    }
    __syncthreads();
    const unsigned selbin = (unsigned)sh_selbin;
    for (int n = tid; n < NBOX; n += 1024) {
        float2 oc = *reinterpret_cast<const float2*>(xb + n * 6 + 4);
        float conf = oc.x * oc.y;
        bool take = false; unsigned key = 0;
        if (conf > CONF_T) {
            key = __float_as_uint(conf) - KEY_BIAS;
            take = ((key >> 16) >= selbin);
        }
        unsigned long long m = __ballot(take);
        unsigned base = 0;
        if (lane == 0 && m) base = atomicAdd(&sh_cnt, (unsigned)__popcll(m));
        base = (unsigned)__shfl((int)base, 0);
        if (take) {
            unsigned pos = base + (unsigned)__popcll(m & ((1ull << lane) - 1ull));
            if (pos < BINCAP)
                cand[pos] = ((unsigned long long)key << 32) | (unsigned)(~(unsigned)n);
        }
    }
    __syncthreads();
    const int C = (int)min(sh_cnt, (unsigned)BINCAP);
    for (int e = tid; e < C; e += 1024) {
        unsigned long long mine = cand[e];
        int rank = 0;
        #pragma unroll 8
        for (int j = 0; j < C; ++j) rank += (cand[j] > mine) ? 1 : 0;
        if (rank < TOPK) keys[rank] = mine;
    }
    __syncthreads();
    unsigned long long kk = keys[tid];
    unsigned key24 = (unsigned)(kk >> 32);
    int n = (int)(~(unsigned)kk);
    bool alive = (kk != 0ull);
    if (n < 0 || n >= NBOX) { n = 0; alive = false; }
    float sc_ = __uint_as_float(key24 + KEY_BIAS);
    float2 p01 = *reinterpret_cast<const float2*>(xb + n * 6);
    float2 p23 = *reinterpret_cast<const float2*>(xb + n * 6 + 2);
    float x1 = p01.x - p23.x * 0.5f, y1 = p01.y - p23.y * 0.5f;
    float x2 = p01.x + p23.x * 0.5f, y2 = p01.y + p23.y * 0.5f;
    float4 mybox = make_float4(x1, y1, x2, y2);
    float my_ar = (x2 - x1) * (y2 - y1);
    bbox[tid] = mybox;
    bar[tid] = my_ar;
    __syncthreads();
    const int cbase = tid & ~63;
    unsigned long long my_mask = 0ull;
    #pragma unroll 4
    for (int i = 0; i < 64; ++i) {
        float4 bi = bbox[cbase + i];
        float ai = bar[cbase + i];
        float xx1 = fmaxf(bi.x, mybox.x);
        float yy1 = fmaxf(bi.y, mybox.y);
        float xx2 = fminf(bi.z, mybox.z);
        float yy2 = fminf(bi.w, mybox.w);
        float iw = fmaxf(xx2 - xx1, 0.0f);
        float ih = fmaxf(yy2 - yy1, 0.0f);
        float inter = iw * ih;
        float iou = inter / (ai + my_ar - inter + 1e-9f);
        if (i < lane && iou > IOU_T) my_mask |= (1ull << i);
    }
    for (int c = 0; c < 16; ++c) {
        if (c > 0 && wv >= c && alive) {
            const int pb = (c - 1) & 1;
            const int m = listn[pb];
            bool sup = false;
            #pragma unroll 2
            for (int t = 0; t < m; ++t) {
                float4 bi = lbox[pb][t];
                float ai = lar[pb][t];
                float xx1 = fmaxf(bi.x, mybox.x);
                float yy1 = fmaxf(bi.y, mybox.y);
                float xx2 = fminf(bi.z, mybox.z);
                float yy2 = fminf(bi.w, mybox.w);
                float iw = fmaxf(xx2 - xx1, 0.0f);
                float ih = fmaxf(yy2 - yy1, 0.0f);
                float inter = iw * ih;
                float iou = inter / (ai + my_ar - inter + 1e-9f);
                sup = sup || (iou > IOU_T);
            }
            alive = !sup;
        }
        if (wv == c) {
            unsigned long long rem = __ballot(alive);
            unsigned long long kept = 0ull;
            while (rem) {
                int i = __ffsll((long long)rem) - 1;
                unsigned long long bit = 1ull << i;
                kept |= bit;
                unsigned long long row = __ballot((unsigned)((my_mask >> i) & 1ull));
                rem &= ~(row | bit);
            }
            alive = (kept >> lane) & 1ull;
            int nk = __popcll(kept);
            int rk = __popcll(kept & ((1ull << lane) - 1ull));
            if (alive) { lbox[c & 1][rk] = mybox; lar[c & 1][rk] = my_ar; }
            if (lane == 0) listn[c & 1] = nk;
        }
        __syncthreads();
    }
    unsigned long long m = __ballot(alive);
    if (lane == 0) wcnt[wv] = __popcll(m);
    __syncthreads();
    if (tid == 0) {
        int acc = 0;
        for (int w2 = 0; w2 < 16; ++w2) { wpre[w2] = acc; acc += wcnt[w2]; }
        sh_total = acc;
    }
    __syncthreads();
    const int rank = wpre[wv] + (int)__popcll(m & ((1ull << lane) - 1ull));
    const int total = sh_total;
    float* __restrict__ ob = out + (size_t)b * MAXDET * 6;
    if (alive && rank < MAXDET) {
        ob[rank * 6 + 0] = mybox.x;
        ob[rank * 6 + 1] = mybox.y;
        ob[rank * 6 + 2] = mybox.z;
        ob[rank * 6 + 3] = mybox.w;
        ob[rank * 6 + 4] = sc_;
        ob[rank * 6 + 5] = 0.0f;
    }
    for (int r = tid; r < MAXDET; r += 1024) {
        if (r >= total) {
            #pragma unroll
            for (int cc = 0; cc < 6; ++cc) ob[r * 6 + cc] = 0.0f;
        }
    }
}

extern "C" void kernel_launch(void* const* d_in, const int* in_sizes, int n_in,
                              void* d_out, int out_size, void* d_ws, size_t ws_size,
                              hipStream_t stream) {
    const float* x = (const float*)d_in[0];
    float* out = (float*)d_out;
    if (ws_size >= (size_t)WS_NEED) {
        char* ws = (char*)d_ws;
        unsigned long long* segs   = (unsigned long long*)(ws + SEGS_OFF);
        unsigned* segcnt           = (unsigned*)(ws + SEGCNT_OFF);
        unsigned* ghist            = (unsigned*)(ws + GHIST_OFF);
        unsigned long long* sorted = (unsigned long long*)(ws + SORTED_OFF);
        float4* sbox               = (float4*)(ws + SBOX_OFF);
        float* sarea               = (float*)(ws + SAREA_OFF);
        unsigned long long* masks  = (unsigned long long*)(ws + MASKS_OFF);
        hipLaunchKernelGGL(k1_extract, dim3(BATCH * 8), dim3(256), 0, stream,
                           x, segs, segcnt, ghist);
        hipLaunchKernelGGL(k2_sort, dim3(BATCH), dim3(1024), 0, stream,
                           x, segs, segcnt, ghist, sorted, sbox, sarea);
        hipLaunchKernelGGL(k3_masks, dim3(34, BATCH), dim3(256), 0, stream,
                           sbox, sarea, masks);
        hipLaunchKernelGGL(k4_resolve, dim3(BATCH), dim3(1024), 0, stream,
                           sorted, sbox, masks, out);
    } else {
        hipLaunchKernelGGL(nms_single_kernel, dim3(BATCH), dim3(1024), 0, stream, x, out);
    }
}